// Round 9
// baseline (627.948 us; speedup 1.0000x reference)
//
#include <hip/hip_runtime.h>

// Chamfer distance: B=8, N=M=8192, D=3, fp32, via bf16 split-precision MFMA.
// R9: KEY INSIGHT -- both chamfer directions are min-reductions of the SAME
// distance matrix D[n,m] (rows=pred, cols=gt). One MFMA tile pass updates
// row-mins (in-reg min3 folds) AND col-mins (in-lane reg tree + shfl_xor(32)
// + ds_min into LDS colkeys, flushed once/block). MFMA count, LDS reads and
// distance-value consumption all HALVE vs R6-R8 (which were pinned 43-47us
// across 3 structural variants). PPW=1 keeps register pressure below the
// cliff R7/R8 hit. 2048 blocks, 24.6KB LDS -> 6 blocks/CU.

#define B_DIM 8
#define N_DIM 8192
#define MT    256               // m-tiles per b
#define MS    4                 // m-splits
#define MTB   (MT / MS)         // 64 m-tiles per block
#define CH    8                 // tiles per staged chunk (8 KB)
#define NC    (MTB / CH)        // 8 chunks
#define BLOCK 256

typedef short  bf16x8 __attribute__((ext_vector_type(8)));
typedef float  f32x16 __attribute__((ext_vector_type(16)));

__device__ __forceinline__ unsigned short bf16_rne(float f) {
    unsigned int u = __float_as_uint(f);
    u += 0x7fffu + ((u >> 16) & 1u);
    return (unsigned short)(u >> 16);
}
__device__ __forceinline__ float bf16f(unsigned short h) {
    return __uint_as_float(((unsigned int)h) << 16);
}
__device__ __forceinline__ unsigned int f32_to_ordered_u32(float f) {
    unsigned int u = __float_as_uint(f);
    return (u & 0x80000000u) ? ~u : (u | 0x80000000u);
}
__device__ __forceinline__ float ordered_u32_to_f32(unsigned int k) {
    return __uint_as_float((k & 0x80000000u) ? (k & 0x7fffffffu) : ~k);
}

// Pack gt-side B-fragments (cols). keys: [0,B*N) row-mins (pred side),
// [B*N, 2*B*N) col-mins (gt side), init 0xFF.
__global__ __launch_bounds__(256) void chamfer_prep(
    const float* __restrict__ gt, unsigned short* __restrict__ bpack,
    unsigned int* __restrict__ keys, float* __restrict__ out)
{
    const int i = blockIdx.x * 256 + threadIdx.x;    // 0 .. 2*B*N-1
    if (i == 0) out[0] = 0.0f;
    keys[i] = 0xFFFFFFFFu;
    if (i >= B_DIM * N_DIM) return;
    const int b = i >> 13, m = i & (N_DIM - 1);
    const float x = gt[3*i+0], y = gt[3*i+1], z = gt[3*i+2];
    const unsigned short hx = bf16_rne(x), hy = bf16_rne(y), hz = bf16_rne(z);
    const unsigned short lx = bf16_rne(x - bf16f(hx));
    const unsigned short ly = bf16_rne(y - bf16f(hy));
    const unsigned short lz = bf16_rne(z - bf16f(hz));
    const float gn = x*x + y*y + z*z;
    const unsigned short gnh = bf16_rne(gn), gnl = bf16_rne(gn - bf16f(gnh));
    const unsigned short one = 0x3F80;
    const int mt = m >> 5, c = m & 31;
    unsigned short* p0 = bpack + ((size_t)(b * MT + mt) * 64 + c) * 8;
    unsigned short* p1 = p0 + 32 * 8;
    // K slots: half0 = gh(xyz) gl(xyz) gh(x,y) ; half1 = gh(z) 1 1 gnh gnl 0 0 0
    bf16x8 h0 = {(short)hx,(short)hy,(short)hz,(short)lx,(short)ly,(short)lz,(short)hx,(short)hy};
    bf16x8 h1 = {(short)hz,(short)one,(short)one,(short)gnh,(short)gnl,0,0,0};
    *(bf16x8*)p0 = h0;
    *(bf16x8*)p1 = h1;
}

__global__ __launch_bounds__(BLOCK, 6) void chamfer_partial(
    const float* __restrict__ pred, const bf16x8* __restrict__ bpack,
    unsigned int* __restrict__ keys)
{
    __shared__ bf16x8 sbuf[2][CH * 64];          // 16 KB double buffer
    __shared__ unsigned int colkeys[MTB * 32];   // 8 KB: block's m-range col-mins
    const int b   = blockIdx.x & 7;
    const int ms  = blockIdx.x >> 3;
    const int w   = threadIdx.x >> 6, lane = threadIdx.x & 63;
    const int half = lane >> 5, col = lane & 31;
    const int tid = threadIdx.x;

    // A fragment: pred points, n-tile per wave (row = col, k-half = half).
    const int ntile = blockIdx.y * 4 + w;
    const int n = ntile * 32 + col;
    const float* pb_ = pred + (size_t)b * N_DIM * 3;
    const float x = pb_[3*n+0], y = pb_[3*n+1], z = pb_[3*n+2];
    const float ax = -2.f*x, ay = -2.f*y, az = -2.f*z;
    const unsigned short ahx = bf16_rne(ax), ahy = bf16_rne(ay), ahz = bf16_rne(az);
    const unsigned short alx = bf16_rne(ax - bf16f(ahx));
    const unsigned short aly = bf16_rne(ay - bf16f(ahy));
    const unsigned short alz = bf16_rne(az - bf16f(ahz));
    const float pn = x*x + y*y + z*z;
    const unsigned short pnh = bf16_rne(pn), pnl = bf16_rne(pn - bf16f(pnh));
    const unsigned short one = 0x3F80;
    bf16x8 a0 = {(short)ahx,(short)ahy,(short)ahz,(short)ahx,(short)ahy,(short)ahz,(short)alx,(short)aly};
    bf16x8 a1 = {(short)alz,(short)pnh,(short)pnl,(short)one,(short)one,0,0,0};
    const bf16x8 afrag = (half == 0) ? a0 : a1;

    const bf16x8* bp = bpack + ((size_t)b * MT + (size_t)ms * MTB) * 64;
    const f32x16 czero = {0.f,0.f,0.f,0.f,0.f,0.f,0.f,0.f,
                          0.f,0.f,0.f,0.f,0.f,0.f,0.f,0.f};
    float best[16];
    #pragma unroll
    for (int r = 0; r < 16; ++r) best[r] = 1e30f;

    // init colkeys
    #pragma unroll
    for (int k = 0; k < (MTB * 32) / BLOCK; ++k)
        colkeys[k * BLOCK + tid] = 0xFFFFFFFFu;

    #define GLL(c, pb) { \
        _Pragma("unroll") for (int i = 0; i < 2; ++i) { \
            const bf16x8* g = bp + (size_t)(c) * (CH*64) + w*128 + i*64 + lane; \
            __builtin_amdgcn_global_load_lds( \
                (const __attribute__((address_space(1))) void*)g, \
                (__attribute__((address_space(3))) void*)&sbuf[pb][w*128 + i*64], \
                16, 0, 0); \
        } }

    GLL(0, 0);
    __syncthreads();

    for (int c = 0; c < NC; ++c) {
        const int pbuf = c & 1;
        if (c + 1 < NC) GLL(c + 1, pbuf ^ 1);
        #pragma unroll
        for (int j = 0; j < CH; j += 2) {
            const bf16x8 b0 = sbuf[pbuf][(j  ) * 64 + lane];
            const bf16x8 b1 = sbuf[pbuf][(j+1) * 64 + lane];
            f32x16 d0 = __builtin_amdgcn_mfma_f32_32x32x16_bf16(afrag, b0, czero, 0, 0, 0);
            f32x16 d1 = __builtin_amdgcn_mfma_f32_32x32x16_bf16(afrag, b1, czero, 0, 0, 0);
            // row-min folds (pred side)
            #pragma unroll
            for (int r = 0; r < 16; ++r)
                best[r] = fminf(fminf(best[r], d0[r]), d1[r]);
            // col-min trees (gt side): min over this lane's 16 rows
            float c0 = fminf(fminf(fminf(d0[0], d0[1]), fminf(d0[2], d0[3])),
                             fminf(fminf(d0[4], d0[5]), fminf(d0[6], d0[7])));
            c0 = fminf(c0, fminf(fminf(fminf(d0[8], d0[9]),  fminf(d0[10], d0[11])),
                                 fminf(fminf(d0[12], d0[13]), fminf(d0[14], d0[15]))));
            float c1 = fminf(fminf(fminf(d1[0], d1[1]), fminf(d1[2], d1[3])),
                             fminf(fminf(d1[4], d1[5]), fminf(d1[6], d1[7])));
            c1 = fminf(c1, fminf(fminf(fminf(d1[8], d1[9]),  fminf(d1[10], d1[11])),
                                 fminf(fminf(d1[12], d1[13]), fminf(d1[14], d1[15]))));
            // combine halves (other half holds the complementary 16 rows)
            c0 = fminf(c0, __shfl_xor(c0, 32, 64));
            c1 = fminf(c1, __shfl_xor(c1, 32, 64));
            if (lane < 32) {
                const int jj = c * CH + j;
                atomicMin(&colkeys[(jj    ) * 32 + col], f32_to_ordered_u32(c0));
                atomicMin(&colkeys[(jj + 1) * 32 + col], f32_to_ordered_u32(c1));
            }
        }
        __syncthreads();
    }

    // flush col-mins: one global atomicMin per key (gt-side region of keys)
    unsigned int* ck = keys + (size_t)B_DIM * N_DIM + (size_t)b * N_DIM + ms * (MTB * 32);
    #pragma unroll
    for (int k = 0; k < (MTB * 32) / BLOCK; ++k) {
        const int idx = k * BLOCK + tid;
        atomicMin(&ck[idx], colkeys[idx]);
    }

    // row-mins: fold 32 m-residue lanes, then atomicMin (MS contributors)
    unsigned int* rk = keys + (size_t)b * N_DIM;
    #pragma unroll
    for (int r = 0; r < 16; ++r) {
        float v = best[r];
        v = fminf(v, __shfl_xor(v, 1,  64));
        v = fminf(v, __shfl_xor(v, 2,  64));
        v = fminf(v, __shfl_xor(v, 4,  64));
        v = fminf(v, __shfl_xor(v, 8,  64));
        v = fminf(v, __shfl_xor(v, 16, 64));
        const int row = (r & 3) + 8 * (r >> 2) + 4 * half;
        if (col == r)
            atomicMin(&rk[ntile * 32 + row], f32_to_ordered_u32(v));
    }
}

__global__ __launch_bounds__(256) void chamfer_reduce(
    const unsigned int* __restrict__ keys, float* __restrict__ out)
{
    const float scale = 100.0f * 0.5f / ((float)B_DIM * (float)N_DIM);
    const int i = (blockIdx.x * 256 + threadIdx.x) * 4;
    const uint4 k = *(const uint4*)(keys + i);
    float s = ordered_u32_to_f32(k.x) + ordered_u32_to_f32(k.y)
            + ordered_u32_to_f32(k.z) + ordered_u32_to_f32(k.w);
    for (int off = 32; off > 0; off >>= 1) s += __shfl_down(s, off, 64);
    __shared__ float wsum[4];
    if ((threadIdx.x & 63) == 0) wsum[threadIdx.x >> 6] = s;
    __syncthreads();
    if (threadIdx.x == 0)
        atomicAdd(out, (wsum[0] + wsum[1] + wsum[2] + wsum[3]) * scale);
}

extern "C" void kernel_launch(void* const* d_in, const int* in_sizes, int n_in,
                              void* d_out, int out_size, void* d_ws, size_t ws_size,
                              hipStream_t stream) {
    const float* pred = (const float*)d_in[0];
    const float* gt   = (const float*)d_in[1];
    float* out = (float*)d_out;
    // ws: [0, 2MiB) packed gt B-fragments ; [2MiB, 2.5MiB) ordered-u32 min keys
    unsigned short* bpack = (unsigned short*)d_ws;
    unsigned int* keys = (unsigned int*)((char*)d_ws + (size_t)B_DIM * MT * 64 * 16);

    chamfer_prep<<<(2 * B_DIM * N_DIM) / 256, 256, 0, stream>>>(gt, bpack, keys, out);

    // (b,ms) x n-chunks = 32 x 64 = 2048 blocks, 6/CU (LDS-limited)
    dim3 grid(B_DIM * MS, N_DIM / (32 * 4));
    chamfer_partial<<<grid, BLOCK, 0, stream>>>(pred, (const bf16x8*)bpack, keys);

    chamfer_reduce<<<(2 * B_DIM * N_DIM) / (256 * 4), 256, 0, stream>>>(keys, out);
}

// Round 10
// 278.202 us; speedup vs baseline: 2.2572x; 2.2572x over previous
//
#include <hip/hip_runtime.h>

// Chamfer distance: B=8, N=M=8192, D=3, fp32, via bf16 split-precision MFMA.
// R10: R9's fused row+col single-pass over D[n,m] was algorithmically right
// (work halved, absmax 0) but __launch_bounds__(,6) capped VGPRs at ~85 ->
// accumulator spill -> 2.8 GB scratch traffic @ 4.8 TB/s = 628us.
// Fixes: launch_bounds(,4) (cap 128), ONE f32x16 MFMA result live at a time
// (fold row mins + col tree before next MFMA). Live set ~60 VGPR, no spill.
// Budget/CU: MFMA 6.8us, LDS ~13us, VALU ~17us -> predict partial 22-28us.

#define B_DIM 8
#define N_DIM 8192
#define MT    256               // m-tiles per b
#define MS    4                 // m-splits
#define MTB   (MT / MS)         // 64 m-tiles per block
#define CH    8                 // tiles per staged chunk (8 KB)
#define NC    (MTB / CH)        // 8 chunks
#define BLOCK 256

typedef short  bf16x8 __attribute__((ext_vector_type(8)));
typedef float  f32x16 __attribute__((ext_vector_type(16)));

__device__ __forceinline__ unsigned short bf16_rne(float f) {
    unsigned int u = __float_as_uint(f);
    u += 0x7fffu + ((u >> 16) & 1u);
    return (unsigned short)(u >> 16);
}
__device__ __forceinline__ float bf16f(unsigned short h) {
    return __uint_as_float(((unsigned int)h) << 16);
}
__device__ __forceinline__ unsigned int f32_to_ordered_u32(float f) {
    unsigned int u = __float_as_uint(f);
    return (u & 0x80000000u) ? ~u : (u | 0x80000000u);
}
__device__ __forceinline__ float ordered_u32_to_f32(unsigned int k) {
    return __uint_as_float((k & 0x80000000u) ? (k & 0x7fffffffu) : ~k);
}

// Pack gt-side B-fragments (cols). keys: [0,B*N) row-mins (pred side),
// [B*N, 2*B*N) col-mins (gt side), init 0xFF.
__global__ __launch_bounds__(256) void chamfer_prep(
    const float* __restrict__ gt, unsigned short* __restrict__ bpack,
    unsigned int* __restrict__ keys, float* __restrict__ out)
{
    const int i = blockIdx.x * 256 + threadIdx.x;    // 0 .. 2*B*N-1
    if (i == 0) out[0] = 0.0f;
    keys[i] = 0xFFFFFFFFu;
    if (i >= B_DIM * N_DIM) return;
    const float x = gt[3*i+0], y = gt[3*i+1], z = gt[3*i+2];
    const unsigned short hx = bf16_rne(x), hy = bf16_rne(y), hz = bf16_rne(z);
    const unsigned short lx = bf16_rne(x - bf16f(hx));
    const unsigned short ly = bf16_rne(y - bf16f(hy));
    const unsigned short lz = bf16_rne(z - bf16f(hz));
    const float gn = x*x + y*y + z*z;
    const unsigned short gnh = bf16_rne(gn), gnl = bf16_rne(gn - bf16f(gnh));
    const unsigned short one = 0x3F80;
    const int b = i >> 13, m = i & (N_DIM - 1);
    const int mt = m >> 5, c = m & 31;
    unsigned short* p0 = bpack + ((size_t)(b * MT + mt) * 64 + c) * 8;
    unsigned short* p1 = p0 + 32 * 8;
    // K slots: half0 = gh(xyz) gl(xyz) gh(x,y) ; half1 = gh(z) 1 1 gnh gnl 0 0 0
    bf16x8 h0 = {(short)hx,(short)hy,(short)hz,(short)lx,(short)ly,(short)lz,(short)hx,(short)hy};
    bf16x8 h1 = {(short)hz,(short)one,(short)one,(short)gnh,(short)gnl,0,0,0};
    *(bf16x8*)p0 = h0;
    *(bf16x8*)p1 = h1;
}

__global__ __launch_bounds__(BLOCK, 4) void chamfer_partial(
    const float* __restrict__ pred, const bf16x8* __restrict__ bpack,
    unsigned int* __restrict__ keys)
{
    __shared__ bf16x8 sbuf[2][CH * 64];          // 16 KB double buffer
    __shared__ unsigned int colkeys[MTB * 32];   // 8 KB: block's m-range col-mins
    const int b   = blockIdx.x & 7;
    const int ms  = blockIdx.x >> 3;
    const int w   = threadIdx.x >> 6, lane = threadIdx.x & 63;
    const int half = lane >> 5, col = lane & 31;
    const int tid = threadIdx.x;

    // A fragment: pred points, n-tile per wave (row = col, k-half = half).
    const int ntile = blockIdx.y * 4 + w;
    const int n = ntile * 32 + col;
    const float* pb_ = pred + (size_t)b * N_DIM * 3;
    const float x = pb_[3*n+0], y = pb_[3*n+1], z = pb_[3*n+2];
    const float ax = -2.f*x, ay = -2.f*y, az = -2.f*z;
    const unsigned short ahx = bf16_rne(ax), ahy = bf16_rne(ay), ahz = bf16_rne(az);
    const unsigned short alx = bf16_rne(ax - bf16f(ahx));
    const unsigned short aly = bf16_rne(ay - bf16f(ahy));
    const unsigned short alz = bf16_rne(az - bf16f(ahz));
    const float pn = x*x + y*y + z*z;
    const unsigned short pnh = bf16_rne(pn), pnl = bf16_rne(pn - bf16f(pnh));
    const unsigned short one = 0x3F80;
    bf16x8 a0 = {(short)ahx,(short)ahy,(short)ahz,(short)ahx,(short)ahy,(short)ahz,(short)alx,(short)aly};
    bf16x8 a1 = {(short)alz,(short)pnh,(short)pnl,(short)one,(short)one,0,0,0};
    const bf16x8 afrag = (half == 0) ? a0 : a1;

    const bf16x8* bp = bpack + ((size_t)b * MT + (size_t)ms * MTB) * 64;
    const f32x16 czero = {0.f,0.f,0.f,0.f,0.f,0.f,0.f,0.f,
                          0.f,0.f,0.f,0.f,0.f,0.f,0.f,0.f};
    float best[16];
    #pragma unroll
    for (int r = 0; r < 16; ++r) best[r] = 1e30f;

    #pragma unroll
    for (int k = 0; k < (MTB * 32) / BLOCK; ++k)
        colkeys[k * BLOCK + tid] = 0xFFFFFFFFu;

    #define GLL(c, pb) { \
        _Pragma("unroll") for (int i = 0; i < 2; ++i) { \
            const bf16x8* g = bp + (size_t)(c) * (CH*64) + w*128 + i*64 + lane; \
            __builtin_amdgcn_global_load_lds( \
                (const __attribute__((address_space(1))) void*)g, \
                (__attribute__((address_space(3))) void*)&sbuf[pb][w*128 + i*64], \
                16, 0, 0); \
        } }

    GLL(0, 0);
    __syncthreads();

    for (int c = 0; c < NC; ++c) {
        const int pbuf = c & 1;
        if (c + 1 < NC) GLL(c + 1, pbuf ^ 1);
        #pragma unroll
        for (int j = 0; j < CH; ++j) {
            const bf16x8 bc = sbuf[pbuf][j * 64 + lane];
            const f32x16 d = __builtin_amdgcn_mfma_f32_32x32x16_bf16(afrag, bc, czero, 0, 0, 0);
            // row-min folds (pred side)
            #pragma unroll
            for (int r = 0; r < 16; ++r) best[r] = fminf(best[r], d[r]);
            // col-min tree (gt side): min over this lane's 16 rows, frees d
            float cm = fminf(fminf(fminf(d[0], d[1]),  fminf(d[2], d[3])),
                             fminf(fminf(d[4], d[5]),  fminf(d[6], d[7])));
            cm = fminf(cm, fminf(fminf(fminf(d[8], d[9]),   fminf(d[10], d[11])),
                                 fminf(fminf(d[12], d[13]), fminf(d[14], d[15]))));
            cm = fminf(cm, __shfl_xor(cm, 32, 64));   // other half's 16 rows
            if (lane < 32)
                atomicMin(&colkeys[(c * CH + j) * 32 + col], f32_to_ordered_u32(cm));
        }
        __syncthreads();
    }

    // flush col-mins: one global atomicMin per key (gt-side region of keys)
    unsigned int* ck = keys + (size_t)B_DIM * N_DIM + (size_t)b * N_DIM + ms * (MTB * 32);
    #pragma unroll
    for (int k = 0; k < (MTB * 32) / BLOCK; ++k) {
        const int idx = k * BLOCK + tid;
        atomicMin(&ck[idx], colkeys[idx]);
    }

    // row-mins: fold 32 m-residue lanes, then atomicMin (MS contributors)
    unsigned int* rk = keys + (size_t)b * N_DIM;
    #pragma unroll
    for (int r = 0; r < 16; ++r) {
        float v = best[r];
        v = fminf(v, __shfl_xor(v, 1,  64));
        v = fminf(v, __shfl_xor(v, 2,  64));
        v = fminf(v, __shfl_xor(v, 4,  64));
        v = fminf(v, __shfl_xor(v, 8,  64));
        v = fminf(v, __shfl_xor(v, 16, 64));
        const int row = (r & 3) + 8 * (r >> 2) + 4 * half;
        if (col == r)
            atomicMin(&rk[ntile * 32 + row], f32_to_ordered_u32(v));
    }
}

__global__ __launch_bounds__(256) void chamfer_reduce(
    const unsigned int* __restrict__ keys, float* __restrict__ out)
{
    const float scale = 100.0f * 0.5f / ((float)B_DIM * (float)N_DIM);
    const int i = (blockIdx.x * 256 + threadIdx.x) * 4;
    const uint4 k = *(const uint4*)(keys + i);
    float s = ordered_u32_to_f32(k.x) + ordered_u32_to_f32(k.y)
            + ordered_u32_to_f32(k.z) + ordered_u32_to_f32(k.w);
    for (int off = 32; off > 0; off >>= 1) s += __shfl_down(s, off, 64);
    __shared__ float wsum[4];
    if ((threadIdx.x & 63) == 0) wsum[threadIdx.x >> 6] = s;
    __syncthreads();
    if (threadIdx.x == 0)
        atomicAdd(out, (wsum[0] + wsum[1] + wsum[2] + wsum[3]) * scale);
}

extern "C" void kernel_launch(void* const* d_in, const int* in_sizes, int n_in,
                              void* d_out, int out_size, void* d_ws, size_t ws_size,
                              hipStream_t stream) {
    const float* pred = (const float*)d_in[0];
    const float* gt   = (const float*)d_in[1];
    float* out = (float*)d_out;
    // ws: [0, 2MiB) packed gt B-fragments ; [2MiB, 2.5MiB) ordered-u32 min keys
    unsigned short* bpack = (unsigned short*)d_ws;
    unsigned int* keys = (unsigned int*)((char*)d_ws + (size_t)B_DIM * MT * 64 * 16);

    chamfer_prep<<<(2 * B_DIM * N_DIM) / 256, 256, 0, stream>>>(gt, bpack, keys, out);

    // (b,ms) x n-chunks = 32 x 64 = 2048 blocks
    dim3 grid(B_DIM * MS, N_DIM / (32 * 4));
    chamfer_partial<<<grid, BLOCK, 0, stream>>>(pred, (const bf16x8*)bpack, keys);

    chamfer_reduce<<<(2 * B_DIM * N_DIM) / (256 * 4), 256, 0, stream>>>(keys, out);
}

// Round 11
// 254.539 us; speedup vs baseline: 2.4670x; 1.0930x over previous
//
#include <hip/hip_runtime.h>

// Chamfer distance: B=8, N=M=8192, D=3, fp32, via bf16 split-precision MFMA.
// R11: fused row+col single pass over D[n,m] (halves MFMA/LDS vs R6-R8).
// R10 still spilled: compiler split the unified RF at accum_offset=64 (64
// arch VGPR + 64 AGPR); reading each d[r] TWICE (row fold + col tree) forced
// all 16 MFMA results into arch VGPRs simultaneously -> best[] spilled ->
// 1.1 GB scratch traffic. Fix: SINGLE use site per d element:
//   t = d[r]; best[r] = fmin(best[r], t); cm = fmin(cm, t);
// (one accvgpr_read, t dead immediately). Live ~45 arch VGPRs, no spill.

#define B_DIM 8
#define N_DIM 8192
#define MT    256               // m-tiles per b
#define MS    4                 // m-splits
#define MTB   (MT / MS)         // 64 m-tiles per block
#define CH    8                 // tiles per staged chunk (8 KB)
#define NC    (MTB / CH)        // 8 chunks
#define BLOCK 256

typedef short  bf16x8 __attribute__((ext_vector_type(8)));
typedef float  f32x16 __attribute__((ext_vector_type(16)));

__device__ __forceinline__ unsigned short bf16_rne(float f) {
    unsigned int u = __float_as_uint(f);
    u += 0x7fffu + ((u >> 16) & 1u);
    return (unsigned short)(u >> 16);
}
__device__ __forceinline__ float bf16f(unsigned short h) {
    return __uint_as_float(((unsigned int)h) << 16);
}
__device__ __forceinline__ unsigned int f32_to_ordered_u32(float f) {
    unsigned int u = __float_as_uint(f);
    return (u & 0x80000000u) ? ~u : (u | 0x80000000u);
}
__device__ __forceinline__ float ordered_u32_to_f32(unsigned int k) {
    return __uint_as_float((k & 0x80000000u) ? (k & 0x7fffffffu) : ~k);
}

// Pack gt-side B-fragments (cols). keys: [0,B*N) row-mins (pred side),
// [B*N, 2*B*N) col-mins (gt side), init 0xFF.
__global__ __launch_bounds__(256) void chamfer_prep(
    const float* __restrict__ gt, unsigned short* __restrict__ bpack,
    unsigned int* __restrict__ keys, float* __restrict__ out)
{
    const int i = blockIdx.x * 256 + threadIdx.x;    // 0 .. 2*B*N-1
    if (i == 0) out[0] = 0.0f;
    keys[i] = 0xFFFFFFFFu;
    if (i >= B_DIM * N_DIM) return;
    const float x = gt[3*i+0], y = gt[3*i+1], z = gt[3*i+2];
    const unsigned short hx = bf16_rne(x), hy = bf16_rne(y), hz = bf16_rne(z);
    const unsigned short lx = bf16_rne(x - bf16f(hx));
    const unsigned short ly = bf16_rne(y - bf16f(hy));
    const unsigned short lz = bf16_rne(z - bf16f(hz));
    const float gn = x*x + y*y + z*z;
    const unsigned short gnh = bf16_rne(gn), gnl = bf16_rne(gn - bf16f(gnh));
    const unsigned short one = 0x3F80;
    const int b = i >> 13, m = i & (N_DIM - 1);
    const int mt = m >> 5, c = m & 31;
    unsigned short* p0 = bpack + ((size_t)(b * MT + mt) * 64 + c) * 8;
    unsigned short* p1 = p0 + 32 * 8;
    // K slots: half0 = gh(xyz) gl(xyz) gh(x,y) ; half1 = gh(z) 1 1 gnh gnl 0 0 0
    bf16x8 h0 = {(short)hx,(short)hy,(short)hz,(short)lx,(short)ly,(short)lz,(short)hx,(short)hy};
    bf16x8 h1 = {(short)hz,(short)one,(short)one,(short)gnh,(short)gnl,0,0,0};
    *(bf16x8*)p0 = h0;
    *(bf16x8*)p1 = h1;
}

__global__ __launch_bounds__(BLOCK, 4) void chamfer_partial(
    const float* __restrict__ pred, const bf16x8* __restrict__ bpack,
    unsigned int* __restrict__ keys)
{
    __shared__ bf16x8 sbuf[2][CH * 64];          // 16 KB double buffer
    __shared__ unsigned int colkeys[MTB * 32];   // 8 KB: block's m-range col-mins
    const int b   = blockIdx.x & 7;
    const int ms  = blockIdx.x >> 3;
    const int w   = threadIdx.x >> 6, lane = threadIdx.x & 63;
    const int half = lane >> 5, col = lane & 31;
    const int tid = threadIdx.x;

    // A fragment: pred points, n-tile per wave (row = col, k-half = half).
    const int ntile = blockIdx.y * 4 + w;
    const int n = ntile * 32 + col;
    const float* pb_ = pred + (size_t)b * N_DIM * 3;
    const float x = pb_[3*n+0], y = pb_[3*n+1], z = pb_[3*n+2];
    const float ax = -2.f*x, ay = -2.f*y, az = -2.f*z;
    const unsigned short ahx = bf16_rne(ax), ahy = bf16_rne(ay), ahz = bf16_rne(az);
    const unsigned short alx = bf16_rne(ax - bf16f(ahx));
    const unsigned short aly = bf16_rne(ay - bf16f(ahy));
    const unsigned short alz = bf16_rne(az - bf16f(ahz));
    const float pn = x*x + y*y + z*z;
    const unsigned short pnh = bf16_rne(pn), pnl = bf16_rne(pn - bf16f(pnh));
    const unsigned short one = 0x3F80;
    bf16x8 a0 = {(short)ahx,(short)ahy,(short)ahz,(short)ahx,(short)ahy,(short)ahz,(short)alx,(short)aly};
    bf16x8 a1 = {(short)alz,(short)pnh,(short)pnl,(short)one,(short)one,0,0,0};
    const bf16x8 afrag = (half == 0) ? a0 : a1;

    const bf16x8* bp = bpack + ((size_t)b * MT + (size_t)ms * MTB) * 64;
    const f32x16 czero = {0.f,0.f,0.f,0.f,0.f,0.f,0.f,0.f,
                          0.f,0.f,0.f,0.f,0.f,0.f,0.f,0.f};
    float best[16];
    #pragma unroll
    for (int r = 0; r < 16; ++r) best[r] = 1e30f;

    #pragma unroll
    for (int k = 0; k < (MTB * 32) / BLOCK; ++k)
        colkeys[k * BLOCK + tid] = 0xFFFFFFFFu;

    #define GLL(c, pb) { \
        _Pragma("unroll") for (int i = 0; i < 2; ++i) { \
            const bf16x8* g = bp + (size_t)(c) * (CH*64) + w*128 + i*64 + lane; \
            __builtin_amdgcn_global_load_lds( \
                (const __attribute__((address_space(1))) void*)g, \
                (__attribute__((address_space(3))) void*)&sbuf[pb][w*128 + i*64], \
                16, 0, 0); \
        } }

    GLL(0, 0);
    __syncthreads();

    for (int c = 0; c < NC; ++c) {
        const int pbuf = c & 1;
        if (c + 1 < NC) GLL(c + 1, pbuf ^ 1);
        #pragma unroll
        for (int j = 0; j < CH; ++j) {
            const bf16x8 bc = sbuf[pbuf][j * 64 + lane];
            const f32x16 d = __builtin_amdgcn_mfma_f32_32x32x16_bf16(afrag, bc, czero, 0, 0, 0);
            // SINGLE use site per d element: one accvgpr_read feeds both mins.
            float cm = 1e30f;
            #pragma unroll
            for (int r = 0; r < 16; ++r) {
                const float t = d[r];
                best[r] = fminf(best[r], t);   // row-min (pred side)
                cm      = fminf(cm, t);        // col-min (gt side), t dies here
            }
            cm = fminf(cm, __shfl_xor(cm, 32, 64));   // other half's 16 rows
            if (lane < 32)
                atomicMin(&colkeys[(c * CH + j) * 32 + col], f32_to_ordered_u32(cm));
        }
        __syncthreads();
    }

    // flush col-mins: one global atomicMin per key (gt-side region of keys)
    unsigned int* ck = keys + (size_t)B_DIM * N_DIM + (size_t)b * N_DIM + ms * (MTB * 32);
    #pragma unroll
    for (int k = 0; k < (MTB * 32) / BLOCK; ++k) {
        const int idx = k * BLOCK + tid;
        atomicMin(&ck[idx], colkeys[idx]);
    }

    // row-mins: fold 32 m-residue lanes, then atomicMin (MS contributors)
    unsigned int* rk = keys + (size_t)b * N_DIM;
    #pragma unroll
    for (int r = 0; r < 16; ++r) {
        float v = best[r];
        v = fminf(v, __shfl_xor(v, 1,  64));
        v = fminf(v, __shfl_xor(v, 2,  64));
        v = fminf(v, __shfl_xor(v, 4,  64));
        v = fminf(v, __shfl_xor(v, 8,  64));
        v = fminf(v, __shfl_xor(v, 16, 64));
        const int row = (r & 3) + 8 * (r >> 2) + 4 * half;
        if (col == r)
            atomicMin(&rk[ntile * 32 + row], f32_to_ordered_u32(v));
    }
}

__global__ __launch_bounds__(256) void chamfer_reduce(
    const unsigned int* __restrict__ keys, float* __restrict__ out)
{
    const float scale = 100.0f * 0.5f / ((float)B_DIM * (float)N_DIM);
    const int i = (blockIdx.x * 256 + threadIdx.x) * 4;
    const uint4 k = *(const uint4*)(keys + i);
    float s = ordered_u32_to_f32(k.x) + ordered_u32_to_f32(k.y)
            + ordered_u32_to_f32(k.z) + ordered_u32_to_f32(k.w);
    for (int off = 32; off > 0; off >>= 1) s += __shfl_down(s, off, 64);
    __shared__ float wsum[4];
    if ((threadIdx.x & 63) == 0) wsum[threadIdx.x >> 6] = s;
    __syncthreads();
    if (threadIdx.x == 0)
        atomicAdd(out, (wsum[0] + wsum[1] + wsum[2] + wsum[3]) * scale);
}

extern "C" void kernel_launch(void* const* d_in, const int* in_sizes, int n_in,
                              void* d_out, int out_size, void* d_ws, size_t ws_size,
                              hipStream_t stream) {
    const float* pred = (const float*)d_in[0];
    const float* gt   = (const float*)d_in[1];
    float* out = (float*)d_out;
    // ws: [0, 2MiB) packed gt B-fragments ; [2MiB, 2.5MiB) ordered-u32 min keys
    unsigned short* bpack = (unsigned short*)d_ws;
    unsigned int* keys = (unsigned int*)((char*)d_ws + (size_t)B_DIM * MT * 64 * 16);

    chamfer_prep<<<(2 * B_DIM * N_DIM) / 256, 256, 0, stream>>>(gt, bpack, keys, out);

    // (b,ms) x n-chunks = 32 x 64 = 2048 blocks
    dim3 grid(B_DIM * MS, N_DIM / (32 * 4));
    chamfer_partial<<<grid, BLOCK, 0, stream>>>(pred, (const bf16x8*)bpack, keys);

    chamfer_reduce<<<(2 * B_DIM * N_DIM) / (256 * 4), 256, 0, stream>>>(keys, out);
}

// Round 12
// 136.793 us; speedup vs baseline: 4.5905x; 1.8608x over previous
//
#include <hip/hip_runtime.h>

// Chamfer distance: B=8, N=M=8192, D=3, fp32, via bf16 split-precision MFMA.
// R12: fused row+col single pass (halves work; validated R9-R11, absmax 0).
// R10/R11 spilled ~1GB/disp because the FULLY-UNROLLED j-loop let the
// scheduler hoist up to 8 independent MFMAs above their consumers ->
// 8 x 16 = 128 live d-regs. Structural fix:
//   - #pragma unroll 1 on the j-loop (no cross-iteration pipelining)
//   - sched_barrier(0) after d is consumed (exactly ONE d live)
// MFMA latency exposed but 4 waves/SIMD cover it; VALU issue (~50cyc/iter,
// 512 wave-iters/SIMD) ~11us is the floor. Predict partial 18-25us, no
// scratch traffic (WRITE < 10MB).

#define B_DIM 8
#define N_DIM 8192
#define MT    256               // m-tiles per b
#define MS    4                 // m-splits
#define MTB   (MT / MS)         // 64 m-tiles per block
#define CH    8                 // tiles per staged chunk (8 KB)
#define NC    (MTB / CH)        // 8 chunks
#define BLOCK 256

typedef short  bf16x8 __attribute__((ext_vector_type(8)));
typedef float  f32x16 __attribute__((ext_vector_type(16)));

__device__ __forceinline__ unsigned short bf16_rne(float f) {
    unsigned int u = __float_as_uint(f);
    u += 0x7fffu + ((u >> 16) & 1u);
    return (unsigned short)(u >> 16);
}
__device__ __forceinline__ float bf16f(unsigned short h) {
    return __uint_as_float(((unsigned int)h) << 16);
}
__device__ __forceinline__ unsigned int f32_to_ordered_u32(float f) {
    unsigned int u = __float_as_uint(f);
    return (u & 0x80000000u) ? ~u : (u | 0x80000000u);
}
__device__ __forceinline__ float ordered_u32_to_f32(unsigned int k) {
    return __uint_as_float((k & 0x80000000u) ? (k & 0x7fffffffu) : ~k);
}

// Pack gt-side B-fragments (cols). keys: [0,B*N) row-mins (pred side),
// [B*N, 2*B*N) col-mins (gt side), init 0xFF.
__global__ __launch_bounds__(256) void chamfer_prep(
    const float* __restrict__ gt, unsigned short* __restrict__ bpack,
    unsigned int* __restrict__ keys, float* __restrict__ out)
{
    const int i = blockIdx.x * 256 + threadIdx.x;    // 0 .. 2*B*N-1
    if (i == 0) out[0] = 0.0f;
    keys[i] = 0xFFFFFFFFu;
    if (i >= B_DIM * N_DIM) return;
    const float x = gt[3*i+0], y = gt[3*i+1], z = gt[3*i+2];
    const unsigned short hx = bf16_rne(x), hy = bf16_rne(y), hz = bf16_rne(z);
    const unsigned short lx = bf16_rne(x - bf16f(hx));
    const unsigned short ly = bf16_rne(y - bf16f(hy));
    const unsigned short lz = bf16_rne(z - bf16f(hz));
    const float gn = x*x + y*y + z*z;
    const unsigned short gnh = bf16_rne(gn), gnl = bf16_rne(gn - bf16f(gnh));
    const unsigned short one = 0x3F80;
    const int b = i >> 13, m = i & (N_DIM - 1);
    const int mt = m >> 5, c = m & 31;
    unsigned short* p0 = bpack + ((size_t)(b * MT + mt) * 64 + c) * 8;
    unsigned short* p1 = p0 + 32 * 8;
    // K slots: half0 = gh(xyz) gl(xyz) gh(x,y) ; half1 = gh(z) 1 1 gnh gnl 0 0 0
    bf16x8 h0 = {(short)hx,(short)hy,(short)hz,(short)lx,(short)ly,(short)lz,(short)hx,(short)hy};
    bf16x8 h1 = {(short)hz,(short)one,(short)one,(short)gnh,(short)gnl,0,0,0};
    *(bf16x8*)p0 = h0;
    *(bf16x8*)p1 = h1;
}

__global__ __launch_bounds__(BLOCK, 4) void chamfer_partial(
    const float* __restrict__ pred, const bf16x8* __restrict__ bpack,
    unsigned int* __restrict__ keys)
{
    __shared__ bf16x8 sbuf[2][CH * 64];          // 16 KB double buffer
    __shared__ unsigned int colkeys[MTB * 32];   // 8 KB: block's m-range col-mins
    const int b   = blockIdx.x & 7;
    const int ms  = blockIdx.x >> 3;
    const int w   = threadIdx.x >> 6, lane = threadIdx.x & 63;
    const int half = lane >> 5, col = lane & 31;
    const int tid = threadIdx.x;

    // A fragment: pred points, n-tile per wave (row = col, k-half = half).
    const int ntile = blockIdx.y * 4 + w;
    const int n = ntile * 32 + col;
    const float* pb_ = pred + (size_t)b * N_DIM * 3;
    const float x = pb_[3*n+0], y = pb_[3*n+1], z = pb_[3*n+2];
    const float ax = -2.f*x, ay = -2.f*y, az = -2.f*z;
    const unsigned short ahx = bf16_rne(ax), ahy = bf16_rne(ay), ahz = bf16_rne(az);
    const unsigned short alx = bf16_rne(ax - bf16f(ahx));
    const unsigned short aly = bf16_rne(ay - bf16f(ahy));
    const unsigned short alz = bf16_rne(az - bf16f(ahz));
    const float pn = x*x + y*y + z*z;
    const unsigned short pnh = bf16_rne(pn), pnl = bf16_rne(pn - bf16f(pnh));
    const unsigned short one = 0x3F80;
    bf16x8 a0 = {(short)ahx,(short)ahy,(short)ahz,(short)ahx,(short)ahy,(short)ahz,(short)alx,(short)aly};
    bf16x8 a1 = {(short)alz,(short)pnh,(short)pnl,(short)one,(short)one,0,0,0};
    const bf16x8 afrag = (half == 0) ? a0 : a1;

    const bf16x8* bp = bpack + ((size_t)b * MT + (size_t)ms * MTB) * 64;
    const f32x16 czero = {0.f,0.f,0.f,0.f,0.f,0.f,0.f,0.f,
                          0.f,0.f,0.f,0.f,0.f,0.f,0.f,0.f};
    float best[16];
    #pragma unroll
    for (int r = 0; r < 16; ++r) best[r] = 1e30f;

    #pragma unroll
    for (int k = 0; k < (MTB * 32) / BLOCK; ++k)
        colkeys[k * BLOCK + tid] = 0xFFFFFFFFu;

    #define GLL(c, pb) { \
        _Pragma("unroll") for (int i = 0; i < 2; ++i) { \
            const bf16x8* g = bp + (size_t)(c) * (CH*64) + w*128 + i*64 + lane; \
            __builtin_amdgcn_global_load_lds( \
                (const __attribute__((address_space(1))) void*)g, \
                (__attribute__((address_space(3))) void*)&sbuf[pb][w*128 + i*64], \
                16, 0, 0); \
        } }

    GLL(0, 0);
    __syncthreads();

    for (int c = 0; c < NC; ++c) {
        const int pbuf = c & 1;
        if (c + 1 < NC) GLL(c + 1, pbuf ^ 1);
        #pragma unroll 1                      // NO cross-iteration MFMA pipelining
        for (int j = 0; j < CH; ++j) {
            const bf16x8 bc = sbuf[pbuf][j * 64 + lane];
            const f32x16 d = __builtin_amdgcn_mfma_f32_32x32x16_bf16(afrag, bc, czero, 0, 0, 0);
            float cm = 1e30f;
            #pragma unroll
            for (int r = 0; r < 16; ++r) {
                const float t = d[r];
                best[r] = fminf(best[r], t);   // row-min (pred side)
                cm      = fminf(cm, t);        // col-min (gt side), t dies here
            }
            cm = fminf(cm, __shfl_xor(cm, 32, 64));   // other half's 16 rows
            if (lane < 32)
                atomicMin(&colkeys[(c * CH + j) * 32 + col], f32_to_ordered_u32(cm));
            __builtin_amdgcn_sched_barrier(0); // d fully dead before next MFMA
        }
        __syncthreads();
    }

    // flush col-mins: one global atomicMin per key (gt-side region of keys)
    unsigned int* ck = keys + (size_t)B_DIM * N_DIM + (size_t)b * N_DIM + ms * (MTB * 32);
    #pragma unroll
    for (int k = 0; k < (MTB * 32) / BLOCK; ++k) {
        const int idx = k * BLOCK + tid;
        atomicMin(&ck[idx], colkeys[idx]);
    }

    // row-mins: fold 32 m-residue lanes, then atomicMin (MS contributors)
    unsigned int* rk = keys + (size_t)b * N_DIM;
    #pragma unroll
    for (int r = 0; r < 16; ++r) {
        float v = best[r];
        v = fminf(v, __shfl_xor(v, 1,  64));
        v = fminf(v, __shfl_xor(v, 2,  64));
        v = fminf(v, __shfl_xor(v, 4,  64));
        v = fminf(v, __shfl_xor(v, 8,  64));
        v = fminf(v, __shfl_xor(v, 16, 64));
        const int row = (r & 3) + 8 * (r >> 2) + 4 * half;
        if (col == r)
            atomicMin(&rk[ntile * 32 + row], f32_to_ordered_u32(v));
    }
}

__global__ __launch_bounds__(256) void chamfer_reduce(
    const unsigned int* __restrict__ keys, float* __restrict__ out)
{
    const float scale = 100.0f * 0.5f / ((float)B_DIM * (float)N_DIM);
    const int i = (blockIdx.x * 256 + threadIdx.x) * 4;
    const uint4 k = *(const uint4*)(keys + i);
    float s = ordered_u32_to_f32(k.x) + ordered_u32_to_f32(k.y)
            + ordered_u32_to_f32(k.z) + ordered_u32_to_f32(k.w);
    for (int off = 32; off > 0; off >>= 1) s += __shfl_down(s, off, 64);
    __shared__ float wsum[4];
    if ((threadIdx.x & 63) == 0) wsum[threadIdx.x >> 6] = s;
    __syncthreads();
    if (threadIdx.x == 0)
        atomicAdd(out, (wsum[0] + wsum[1] + wsum[2] + wsum[3]) * scale);
}

extern "C" void kernel_launch(void* const* d_in, const int* in_sizes, int n_in,
                              void* d_out, int out_size, void* d_ws, size_t ws_size,
                              hipStream_t stream) {
    const float* pred = (const float*)d_in[0];
    const float* gt   = (const float*)d_in[1];
    float* out = (float*)d_out;
    // ws: [0, 2MiB) packed gt B-fragments ; [2MiB, 2.5MiB) ordered-u32 min keys
    unsigned short* bpack = (unsigned short*)d_ws;
    unsigned int* keys = (unsigned int*)((char*)d_ws + (size_t)B_DIM * MT * 64 * 16);

    chamfer_prep<<<(2 * B_DIM * N_DIM) / 256, 256, 0, stream>>>(gt, bpack, keys, out);

    // (b,ms) x n-chunks = 32 x 64 = 2048 blocks
    dim3 grid(B_DIM * MS, N_DIM / (32 * 4));
    chamfer_partial<<<grid, BLOCK, 0, stream>>>(pred, (const bf16x8*)bpack, keys);

    chamfer_reduce<<<(2 * B_DIM * N_DIM) / (256 * 4), 256, 0, stream>>>(keys, out);
}